// Round 15
// baseline (109.352 us; speedup 1.0000x reference)
//
#include <hip/hip_runtime.h>

// Event-to-image: B=16, N=500000 events (t,x,y,p) f32 -> (16,720,1280,3) f32.
// Last-event-wins per pixel: p==1 -> (0,255,255); p==0 -> (255,0,255);
// untouched -> (255,255,510). Order-independent via max over
// key = ((event_idx+1)<<1)|p (20 bits), pk = pos<<20 | key,
// pos = (y&1)*1280 + x (12 bits) -- 2-row bands.
//
// R15 = R14 scatter (batched unguarded loads, ~29us measured) + render
// restructured: NO scan, NO binary search, NO LUT. Thread group s=t>>2
// (4 lanes x 62 segments) walks its own segment's ~22 events directly
// (lane-strided consecutive reads, nt). R14's render was ~52us vs ~30us
// floor; the removed per-event 7-deep LDS-dependent search chain and scan
// preamble are the candidates for that slack.

#define WIDTH   1280
#define HEIGHT  720
#define BATCH   16
#define NEV     500000
#define THREADS 512                         // scatter block
#define EPT     16
#define EVPB    (THREADS * EPT)             // 8192 events per block
#define BPB     ((NEV + EVPB - 1) / EVPB)   // 62 blocks per batch
#define NBLK    (BATCH * BPB)               // 992
#define NBANDS  360                         // 2-row bands per batch
#define PH      (NBANDS + 1)                // 361 prefix entries per block
#define RTHREADS 256                        // render block

typedef float f4 __attribute__((ext_vector_type(4)));

// ws layout: [0, NBLK*PH*4)=pref_g (1.43 MB); [0x400000, +NBLK*EVPB*4)=bins (32.5 MB)

__global__ __launch_bounds__(THREADS, 8) void scatter_k(const float4* __restrict__ ev,
                                                        unsigned int* __restrict__ pref_g,
                                                        unsigned int* __restrict__ bins) {
    __shared__ unsigned int hist[NBANDS];
    __shared__ unsigned int offs[NBANDS];
    __shared__ unsigned int wtot[8];
    __shared__ unsigned int stage[EVPB];     // 32 KB (total ~34.9 KB -> 4 blocks/CU)

    int t = threadIdx.x;
    int batch = blockIdx.x / BPB;
    int blk   = blockIdx.x % BPB;
    int ev0   = blk * EVPB;
    int cnt   = NEV - ev0; if (cnt > EVPB) cnt = EVPB;
    const f4* bevv = (const f4*)(ev + (size_t)batch * NEV + ev0);

    if (t < NBANDS) hist[t] = 0u;
    __syncthreads();

    // pass 1: ONE global read (nt), pack to registers, histogram
    unsigned int pkd[EPT];                   // y<<12 | x<<1 | p ; 0xFFFFFFFF = tail
    if (cnt == EVPB) {
        // full block (61/62): unguarded, batches of 4 loads then 4 atomics
#pragma unroll
        for (int h = 0; h < EPT / 4; ++h) {
            f4 vv[4];
#pragma unroll
            for (int k = 0; k < 4; ++k)
                vv[k] = __builtin_nontemporal_load(&bevv[t + (h * 4 + k) * THREADS]);
#pragma unroll
            for (int k = 0; k < 4; ++k) {
                unsigned int yi = (unsigned int)(int)vv[k].z;
                unsigned int xi = (unsigned int)(int)vv[k].y;
                unsigned int pb = (vv[k].w == 1.0f) ? 1u : 0u;
                pkd[h * 4 + k] = (yi << 12) | (xi << 1) | pb;
                atomicAdd(&hist[yi >> 1], 1u);
            }
        }
    } else {
#pragma unroll
        for (int k = 0; k < EPT; ++k) {
            int e = t + k * THREADS;
            unsigned int c = 0xFFFFFFFFu;
            if (e < cnt) {
                f4 v = __builtin_nontemporal_load(&bevv[e]);
                unsigned int yi = (unsigned int)(int)v.z;
                unsigned int xi = (unsigned int)(int)v.y;
                unsigned int pb = (v.w == 1.0f) ? 1u : 0u;
                c = (yi << 12) | (xi << 1) | pb;
                atomicAdd(&hist[yi >> 1], 1u);
            }
            pkd[k] = c;
        }
    }
    __syncthreads();

    // exclusive prefix over 360 bands: threads 0..89 own 4 bands; shfl scan
    unsigned int own = 0u;
    int b4 = t * 4;
    if (t < 90) own = hist[b4] + hist[b4 + 1] + hist[b4 + 2] + hist[b4 + 3];
    unsigned int incl = own;
    for (int d = 1; d < 64; d <<= 1) {
        unsigned int n = __shfl_up(incl, d);
        if ((t & 63) >= d) incl += n;
    }
    if ((t & 63) == 63) wtot[t >> 6] = incl;   // waves 2..7 contribute 0
    __syncthreads();
    unsigned int wbase = 0u;
    for (int w = 0; w < (t >> 6); ++w) wbase += wtot[w];
    unsigned int total = 0u;
    for (int w = 0; w < 8; ++w) total += wtot[w];        // == cnt
    if (t < 90) {
        unsigned int run = wbase + incl - own;
        offs[b4] = run;          run += hist[b4];
        offs[b4 + 1] = run;      run += hist[b4 + 1];
        offs[b4 + 2] = run;      run += hist[b4 + 2];
        offs[b4 + 3] = run;
    }
    __syncthreads();

    // publish per-block band prefix BEFORE pass 2 mutates offs
    unsigned int* pg = pref_g + (size_t)blockIdx.x * PH;
    if (t < PH) pg[t] = (t < NBANDS) ? offs[t] : total;
    __syncthreads();

    // pass 2: from REGISTERS, rank, place sorted in stage
    if (cnt == EVPB) {
#pragma unroll
        for (int k = 0; k < EPT; ++k) {
            unsigned int c   = pkd[k];
            unsigned int yi  = c >> 12;
            unsigned int xi  = (c >> 1) & 0x7FFu;
            unsigned int pos = (yi & 1u) * 1280u + xi;
            unsigned int e   = (unsigned int)(t + k * THREADS);
            unsigned int pk  = (pos << 20)
                             | (((unsigned int)ev0 + e + 1u) << 1) | (c & 1u);
            unsigned int slot = atomicAdd(&offs[yi >> 1], 1u);
            stage[slot] = pk;
        }
    } else {
#pragma unroll
        for (int k = 0; k < EPT; ++k) {
            unsigned int c = pkd[k];
            if (c != 0xFFFFFFFFu) {
                unsigned int yi  = c >> 12;
                unsigned int xi  = (c >> 1) & 0x7FFu;
                unsigned int pos = (yi & 1u) * 1280u + xi;
                unsigned int e   = (unsigned int)(t + k * THREADS);
                unsigned int pk  = (pos << 20)
                                 | (((unsigned int)ev0 + e + 1u) << 1) | (c & 1u);
                unsigned int slot = atomicAdd(&offs[yi >> 1], 1u);
                stage[slot] = pk;
            }
        }
    }
    __syncthreads();

    // write the sorted chunk, fully coalesced (keep in L2/L3 for render)
    uint4* dst = (uint4*)(bins + (size_t)blockIdx.x * EVPB);
    const uint4* src = (const uint4*)stage;
    for (int k = t; k < EVPB / 4; k += THREADS)
        dst[k] = src[k];
}

__global__ __launch_bounds__(RTHREADS) void render_k(const unsigned int* __restrict__ pref_g,
                                                     const unsigned int* __restrict__ bins,
                                                     float4* __restrict__ out) {
    __shared__ unsigned int win[2 * WIDTH];  // 2560 px, 10 KB
    __shared__ unsigned int segbase[BPB];
    __shared__ unsigned int segcnt[BPB];

    int t = threadIdx.x;
    int bandid = blockIdx.x;                 // batch*360 + band
    int batch = bandid / NBANDS;
    int band  = bandid - batch * NBANDS;

    // issue the scattered pref loads first, zero win while they fly
    unsigned int p0 = 0u, p1 = 0u;
    if (t < BPB) {
        const unsigned int* pg = pref_g + (size_t)(batch * BPB + t) * PH + band;
        p0 = pg[0]; p1 = pg[1];
    }
    for (int x = t; x < 2 * WIDTH; x += RTHREADS) win[x] = 0u;
    if (t < BPB) {
        segbase[t] = (unsigned int)((batch * BPB + t) * EVPB) + p0;
        segcnt[t]  = p1 - p0;
    }
    __syncthreads();

    // direct gather: 4 lanes per segment, no scan / no search / no LUT
    int s = t >> 2, l = t & 3;
    if (s < BPB) {
        unsigned int base = segbase[s];
        unsigned int cn   = segcnt[s];       // ~22
        for (unsigned int i = (unsigned int)l; i < cn; i += 4) {
            unsigned int pk = __builtin_nontemporal_load(&bins[base + i]);
            atomicMax(&win[pk >> 20], pk & 0xFFFFFu);   // LDS atomic
        }
    }
    __syncthreads();

    // write two image rows: 2560 px * 3 ch = 1920 float4; one float4 per
    // thread per iteration -> lane-contiguous 1024B per store instruction
    f4* orow = (f4*)out + (size_t)bandid * (2 * WIDTH * 3 / 4);
    for (int j = t; j < 2 * WIDTH * 3 / 4; j += RTHREADS) {
        float vals[4];
#pragma unroll
        for (int c = 0; c < 4; ++c) {
            int fi = j * 4 + c;
            int px = fi / 3;
            int ch = fi - px * 3;
            unsigned int k = win[px];
            float val;
            if (k == 0u) val = (ch == 2) ? 510.0f : 255.0f;
            else if (ch == 2) val = 255.0f;
            else if (ch == 0) val = (k & 1u) ? 0.0f : 255.0f;
            else              val = (k & 1u) ? 255.0f : 0.0f;
            vals[c] = val;
        }
        f4 o = { vals[0], vals[1], vals[2], vals[3] };
        __builtin_nontemporal_store(o, orow + j);
    }
}

extern "C" void kernel_launch(void* const* d_in, const int* in_sizes, int n_in,
                              void* d_out, int out_size, void* d_ws, size_t ws_size,
                              hipStream_t stream) {
    const float4* ev = (const float4*)d_in[0];
    unsigned int* pref_g = (unsigned int*)d_ws;
    unsigned int* bins   = (unsigned int*)((char*)d_ws + 0x400000);
    float4* out = (float4*)d_out;

    scatter_k<<<NBLK, THREADS, 0, stream>>>(ev, pref_g, bins);
    render_k<<<BATCH * NBANDS, RTHREADS, 0, stream>>>(pref_g, bins, out);
}

// Round 16
// 88.797 us; speedup vs baseline: 1.2315x; 1.2315x over previous
//
#include <hip/hip_runtime.h>

// Event-to-image: B=16, N=500000 events (t,x,y,p) f32 -> (16,720,1280,3) f32.
// Last-event-wins per pixel: p==1 -> (0,255,255); p==0 -> (255,0,255);
// untouched -> (255,255,510). Order-independent via max over
// key = ((event_idx+1)<<1)|p (20 bits), pk = pos<<20 | key,
// pos = (y%3)*1280 + x (12 bits, <3840) -- 3-ROW BANDS (240/batch, fits a byte).
//
// R16: render's 62-segment merge (scattered pref preamble + scan + per-event
// segment resolve) was the ~22us slack (R15 proved the search itself wasn't).
// Scatter now deposits each band's events CONTIGUOUSLY in global bins:
// fixed 3072-event region per (batch,band) (lambda~2083, 21 sigma), runs
// reserved via one atomicAdd(gcount, hist[band]) per block-band, copy-out
// dest = adj[band] + e (runs of ~34 consecutive dwords -> line-coalesced).
// pref_g and render's whole preamble die; render = one coalesced read +
// LDS atomicMax + proven interleaved nt write of 3 rows.

#define WIDTH   1280
#define HEIGHT  720
#define BATCH   16
#define NEV     500000
#define THREADS 512                         // scatter block
#define EPT     16
#define EVPB    (THREADS * EPT)             // 8192 events per block
#define BPB     ((NEV + EVPB - 1) / EVPB)   // 62 blocks per batch
#define NBLK    (BATCH * BPB)               // 992
#define NBANDS  240                         // 3-row bands per batch
#define NBTOT   (BATCH * NBANDS)            // 3840 band regions
#define BANDCAP 3072                        // events per region (21 sigma)
#define RTHREADS 256                        // render block
#define BPX     (3 * WIDTH)                 // 3840 pixels per band

typedef float f4 __attribute__((ext_vector_type(4)));

// ws layout: [0, NBTOT*4)=gcount (15KB); [0x10000, +NBTOT*BANDCAP*4)=bins (45MB)

__global__ __launch_bounds__(THREADS, 8) void scatter_k(const float4* __restrict__ ev,
                                                        unsigned int* __restrict__ gcount,
                                                        unsigned int* __restrict__ bins) {
    __shared__ unsigned int hist[NBANDS];
    __shared__ unsigned int offs[NBANDS];
    __shared__ unsigned int adj[NBANDS];
    __shared__ unsigned int stage[EVPB];         // 32 KB
    __shared__ unsigned char bandidx[EVPB];      // 8 KB

    int t = threadIdx.x;
    int batch = blockIdx.x / BPB;
    int blk   = blockIdx.x % BPB;
    int ev0   = blk * EVPB;
    int cnt   = NEV - ev0; if (cnt > EVPB) cnt = EVPB;
    const f4* bevv = (const f4*)(ev + (size_t)batch * NEV + ev0);

    if (t < NBANDS) hist[t] = 0u;
    __syncthreads();

    // pass 1: ONE global read (nt, batched x4 for MLP), pack to registers
    unsigned int pkd[EPT];     // band<<24 | y<<12 | x<<1 | p ; 0xFFFFFFFF = tail
    if (cnt == EVPB) {
#pragma unroll
        for (int h = 0; h < EPT / 4; ++h) {
            f4 vv[4];
#pragma unroll
            for (int k = 0; k < 4; ++k)
                vv[k] = __builtin_nontemporal_load(&bevv[t + (h * 4 + k) * THREADS]);
#pragma unroll
            for (int k = 0; k < 4; ++k) {
                unsigned int yi = (unsigned int)(int)vv[k].z;
                unsigned int xi = (unsigned int)(int)vv[k].y;
                unsigned int pb = (vv[k].w == 1.0f) ? 1u : 0u;
                unsigned int bd = yi / 3u;
                pkd[h * 4 + k] = (bd << 24) | (yi << 12) | (xi << 1) | pb;
                atomicAdd(&hist[bd], 1u);
            }
        }
    } else {
#pragma unroll
        for (int k = 0; k < EPT; ++k) {
            int e = t + k * THREADS;
            unsigned int c = 0xFFFFFFFFu;
            if (e < cnt) {
                f4 v = __builtin_nontemporal_load(&bevv[e]);
                unsigned int yi = (unsigned int)(int)v.z;
                unsigned int xi = (unsigned int)(int)v.y;
                unsigned int pb = (v.w == 1.0f) ? 1u : 0u;
                unsigned int bd = yi / 3u;
                c = (bd << 24) | (yi << 12) | (xi << 1) | pb;
                atomicAdd(&hist[bd], 1u);
            }
            pkd[k] = c;
        }
    }
    __syncthreads();

    // exclusive prefix over 240 bands: wave-0 only, threads 0..59 own 4 bands
    if (t < 60) {
        int b4 = t * 4;
        unsigned int own = hist[b4] + hist[b4 + 1] + hist[b4 + 2] + hist[b4 + 3];
        unsigned int incl = own;
        for (int d = 1; d < 64; d <<= 1) {
            unsigned int n = __shfl_up(incl, d);
            if (t >= d) incl += n;
        }
        unsigned int run = incl - own;
        offs[b4] = run;          run += hist[b4];
        offs[b4 + 1] = run;      run += hist[b4 + 1];
        offs[b4 + 2] = run;      run += hist[b4 + 2];
        offs[b4 + 3] = run;
    }
    __syncthreads();

    // pass 2: from REGISTERS, rank, place band-sorted into stage (+bandidx)
    if (cnt == EVPB) {
#pragma unroll
        for (int k = 0; k < EPT; ++k) {
            unsigned int c   = pkd[k];
            unsigned int bd  = c >> 24;
            unsigned int yi  = (c >> 12) & 0x3FFu;
            unsigned int xi  = (c >> 1) & 0x7FFu;
            unsigned int pos = (yi - bd * 3u) * 1280u + xi;
            unsigned int e   = (unsigned int)(t + k * THREADS);
            unsigned int pk  = (pos << 20)
                             | (((unsigned int)ev0 + e + 1u) << 1) | (c & 1u);
            unsigned int slot = atomicAdd(&offs[bd], 1u);
            stage[slot] = pk;
            bandidx[slot] = (unsigned char)bd;
        }
    } else {
#pragma unroll
        for (int k = 0; k < EPT; ++k) {
            unsigned int c = pkd[k];
            if (c != 0xFFFFFFFFu) {
                unsigned int bd  = c >> 24;
                unsigned int yi  = (c >> 12) & 0x3FFu;
                unsigned int xi  = (c >> 1) & 0x7FFu;
                unsigned int pos = (yi - bd * 3u) * 1280u + xi;
                unsigned int e   = (unsigned int)(t + k * THREADS);
                unsigned int pk  = (pos << 20)
                                 | (((unsigned int)ev0 + e + 1u) << 1) | (c & 1u);
                unsigned int slot = atomicAdd(&offs[bd], 1u);
                stage[slot] = pk;
                bandidx[slot] = (unsigned char)bd;
            }
        }
    }
    __syncthreads();

    // reserve contiguous global runs: one atomicAdd per non-empty band
    if (t < NBANDS) {
        unsigned int h = hist[t];
        unsigned int rb = h ? atomicAdd(&gcount[batch * NBANDS + t], h) : 0u;
        // dest = adj[band] + e ; e in [start, start+h), start = offs[t]-h
        adj[t] = (unsigned int)(batch * NBANDS + t) * BANDCAP + rb - (offs[t] - h);
    }
    __syncthreads();

    // copy-out: runs of ~34 consecutive dwords -> line-coalesced stores
    if (cnt == EVPB) {
#pragma unroll
        for (int k = 0; k < EPT; ++k) {
            int e = t + k * THREADS;
            unsigned int s  = stage[e];
            unsigned int bd = bandidx[e];
            bins[adj[bd] + (unsigned int)e] = s;
        }
    } else {
        for (int e = t; e < cnt; e += THREADS) {
            unsigned int s  = stage[e];
            unsigned int bd = bandidx[e];
            bins[adj[bd] + (unsigned int)e] = s;
        }
    }
}

__global__ __launch_bounds__(RTHREADS) void render_k(const unsigned int* __restrict__ gcount,
                                                     const unsigned int* __restrict__ bins,
                                                     float4* __restrict__ out) {
    __shared__ unsigned int win[BPX];        // 3840 px, 15 KB

    int t = threadIdx.x;
    int bandid = blockIdx.x;                 // batch*240 + band

    unsigned int cnt = gcount[bandid];
    if (cnt > BANDCAP) cnt = BANDCAP;

    for (int x = t; x < BPX; x += RTHREADS) win[x] = 0u;
    __syncthreads();

    // gather: ONE contiguous coalesced run, no segments/scan/search
    const unsigned int* bb = bins + (size_t)bandid * BANDCAP;
    for (unsigned int j = t; j < cnt; j += RTHREADS) {
        unsigned int pk = __builtin_nontemporal_load(&bb[j]);
        atomicMax(&win[pk >> 20], pk & 0xFFFFFu);   // LDS atomic
    }
    __syncthreads();

    // write three image rows: 3840 px * 3 ch = 2880 float4; one float4 per
    // thread per iteration -> lane-contiguous 1024B per store instruction
    f4* orow = (f4*)out + (size_t)bandid * (BPX * 3 / 4);
    for (int j = t; j < BPX * 3 / 4; j += RTHREADS) {
        float vals[4];
#pragma unroll
        for (int c = 0; c < 4; ++c) {
            int fi = j * 4 + c;
            int px = fi / 3;
            int ch = fi - px * 3;
            unsigned int k = win[px];
            float val;
            if (k == 0u) val = (ch == 2) ? 510.0f : 255.0f;
            else if (ch == 2) val = 255.0f;
            else if (ch == 0) val = (k & 1u) ? 0.0f : 255.0f;
            else              val = (k & 1u) ? 255.0f : 0.0f;
            vals[c] = val;
        }
        f4 o = { vals[0], vals[1], vals[2], vals[3] };
        __builtin_nontemporal_store(o, orow + j);
    }
}

extern "C" void kernel_launch(void* const* d_in, const int* in_sizes, int n_in,
                              void* d_out, int out_size, void* d_ws, size_t ws_size,
                              hipStream_t stream) {
    const float4* ev = (const float4*)d_in[0];
    unsigned int* gcount = (unsigned int*)d_ws;
    unsigned int* bins   = (unsigned int*)((char*)d_ws + 0x10000);
    float4* out = (float4*)d_out;

    hipMemsetAsync(gcount, 0, NBTOT * sizeof(unsigned int), stream);
    scatter_k<<<NBLK, THREADS, 0, stream>>>(ev, gcount, bins);
    render_k<<<NBTOT, RTHREADS, 0, stream>>>(gcount, bins, out);
}

// Round 17
// 81.728 us; speedup vs baseline: 1.3380x; 1.0865x over previous
//
#include <hip/hip_runtime.h>

// Event-to-image: B=16, N=500000 events (t,x,y,p) f32 -> (16,720,1280,3) f32.
// Last-event-wins per pixel: p==1 -> (0,255,255); p==0 -> (255,0,255);
// untouched -> (255,255,510). Order-independent via max over
// key = ((event_idx+1)<<1)|p (20 bits), pk = pos<<20 | key,
// pos = (y - 3*band)*1280 + x (<3840, 12 bits) -- 3-ROW BANDS (240/batch).
//
// R17 = R14 (80.8us best) with render per-block overheads amortized:
// (1) 3-row bands: 3840 render blocks (was 5760), 1.5x output per block ->
//     preamble/zero/scan/barrier cost per byte -33%; scatter tables shrink.
// (2) band-major pref layout pref[(band*16+batch)*62+blk]: render preamble =
//     two coalesced 62-dword loads (4 lines) instead of 62 scattered lines;
//     scatter publish becomes 241 scattered 4B stores (L2-merged, cheap).
// (3) R15 overlap (issue pref, zero win while in flight) + proven gather
//     (binary search) + proven interleaved nt float4 stores.

#define WIDTH   1280
#define HEIGHT  720
#define BATCH   16
#define NEV     500000
#define THREADS 512                         // scatter block
#define EPT     16
#define EVPB    (THREADS * EPT)             // 8192 events per block
#define BPB     ((NEV + EVPB - 1) / EVPB)   // 62 blocks per batch
#define NBLK    (BATCH * BPB)               // 992
#define NBANDS  240                         // 3-row bands per batch
#define PH      (NBANDS + 1)                // 241 prefix rows
#define RTHREADS 256                        // render block
#define BPX     (3 * WIDTH)                 // 3840 pixels per band

typedef float f4 __attribute__((ext_vector_type(4)));

// ws layout: [0, PH*BATCH*BPB*4)=pref_g (956 KB, band-major);
//            [0x400000, +NBLK*EVPB*4)=bins (32.5 MB)

__global__ __launch_bounds__(THREADS, 8) void scatter_k(const float4* __restrict__ ev,
                                                        unsigned int* __restrict__ pref_g,
                                                        unsigned int* __restrict__ bins) {
    __shared__ unsigned int hist[NBANDS];
    __shared__ unsigned int offs[NBANDS];
    __shared__ unsigned int stage[EVPB];     // 32 KB (total ~34 KB -> 4 blocks/CU)

    int t = threadIdx.x;
    int batch = blockIdx.x / BPB;
    int blk   = blockIdx.x % BPB;
    int ev0   = blk * EVPB;
    int cnt   = NEV - ev0; if (cnt > EVPB) cnt = EVPB;
    const f4* bevv = (const f4*)(ev + (size_t)batch * NEV + ev0);

    if (t < NBANDS) hist[t] = 0u;
    __syncthreads();

    // pass 1: ONE global read (nt, batched x4 for MLP), pack to registers
    unsigned int pkd[EPT];   // bd<<22 | y<<12 | x<<1 | p ; 0xFFFFFFFF = tail
    if (cnt == EVPB) {
#pragma unroll
        for (int h = 0; h < EPT / 4; ++h) {
            f4 vv[4];
#pragma unroll
            for (int k = 0; k < 4; ++k)
                vv[k] = __builtin_nontemporal_load(&bevv[t + (h * 4 + k) * THREADS]);
#pragma unroll
            for (int k = 0; k < 4; ++k) {
                unsigned int yi = (unsigned int)(int)vv[k].z;
                unsigned int xi = (unsigned int)(int)vv[k].y;
                unsigned int pb = (vv[k].w == 1.0f) ? 1u : 0u;
                unsigned int bd = yi / 3u;
                pkd[h * 4 + k] = (bd << 22) | (yi << 12) | (xi << 1) | pb;
                atomicAdd(&hist[bd], 1u);
            }
        }
    } else {
#pragma unroll
        for (int k = 0; k < EPT; ++k) {
            int e = t + k * THREADS;
            unsigned int c = 0xFFFFFFFFu;
            if (e < cnt) {
                f4 v = __builtin_nontemporal_load(&bevv[e]);
                unsigned int yi = (unsigned int)(int)v.z;
                unsigned int xi = (unsigned int)(int)v.y;
                unsigned int pb = (v.w == 1.0f) ? 1u : 0u;
                unsigned int bd = yi / 3u;
                c = (bd << 22) | (yi << 12) | (xi << 1) | pb;
                atomicAdd(&hist[bd], 1u);
            }
            pkd[k] = c;
        }
    }
    __syncthreads();

    // exclusive prefix over 240 bands: wave 0 only, threads 0..59 own 4 bands
    if (t < 60) {
        int b4 = t * 4;
        unsigned int own = hist[b4] + hist[b4 + 1] + hist[b4 + 2] + hist[b4 + 3];
        unsigned int incl = own;
        for (int d = 1; d < 64; d <<= 1) {
            unsigned int n = __shfl_up(incl, d);
            if (t >= d) incl += n;
        }
        unsigned int run = incl - own;
        offs[b4] = run;          run += hist[b4];
        offs[b4 + 1] = run;      run += hist[b4 + 1];
        offs[b4 + 2] = run;      run += hist[b4 + 2];
        offs[b4 + 3] = run;
    }
    __syncthreads();

    // publish band-major prefix BEFORE pass 2 mutates offs:
    // pref[(r*BATCH + batch)*BPB + blk]; row NBANDS = total (=cnt)
    {
        unsigned int* pp = pref_g + (size_t)batch * BPB + blk;
        for (int r = t; r < PH; r += THREADS)
            pp[(size_t)r * (BATCH * BPB)] = (r < NBANDS) ? offs[r] : (unsigned int)cnt;
    }
    __syncthreads();

    // pass 2: from REGISTERS, rank, place band-sorted into stage
    if (cnt == EVPB) {
#pragma unroll
        for (int k = 0; k < EPT; ++k) {
            unsigned int c   = pkd[k];
            unsigned int bd  = c >> 22;
            unsigned int yi  = (c >> 12) & 0x3FFu;
            unsigned int xi  = (c >> 1) & 0x7FFu;
            unsigned int pos = (yi - bd * 3u) * 1280u + xi;
            unsigned int e   = (unsigned int)(t + k * THREADS);
            unsigned int pk  = (pos << 20)
                             | (((unsigned int)ev0 + e + 1u) << 1) | (c & 1u);
            unsigned int slot = atomicAdd(&offs[bd], 1u);
            stage[slot] = pk;
        }
    } else {
#pragma unroll
        for (int k = 0; k < EPT; ++k) {
            unsigned int c = pkd[k];
            if (c != 0xFFFFFFFFu) {
                unsigned int bd  = c >> 22;
                unsigned int yi  = (c >> 12) & 0x3FFu;
                unsigned int xi  = (c >> 1) & 0x7FFu;
                unsigned int pos = (yi - bd * 3u) * 1280u + xi;
                unsigned int e   = (unsigned int)(t + k * THREADS);
                unsigned int pk  = (pos << 20)
                                 | (((unsigned int)ev0 + e + 1u) << 1) | (c & 1u);
                unsigned int slot = atomicAdd(&offs[bd], 1u);
                stage[slot] = pk;
            }
        }
    }
    __syncthreads();

    // write the sorted chunk, fully coalesced (keep in L2/L3 for render)
    uint4* dst = (uint4*)(bins + (size_t)blockIdx.x * EVPB);
    const uint4* src = (const uint4*)stage;
    for (int k = t; k < EVPB / 4; k += THREADS)
        dst[k] = src[k];
}

__global__ __launch_bounds__(RTHREADS) void render_k(const unsigned int* __restrict__ pref_g,
                                                     const unsigned int* __restrict__ bins,
                                                     float4* __restrict__ out) {
    __shared__ unsigned int win[BPX];        // 3840 px, 15 KB
    __shared__ unsigned int segbase[BPB];
    __shared__ unsigned int segpref[65];

    int t = threadIdx.x;
    int bandid = blockIdx.x;                 // batch*240 + band
    int batch = bandid / NBANDS;
    int band  = bandid - batch * NBANDS;

    // issue the two coalesced pref rows first; zero win while they fly
    unsigned int p0 = 0u, p1 = 0u;
    if (t < BPB) {
        const unsigned int* r0 = pref_g + ((size_t)band * BATCH + batch) * BPB;
        const unsigned int* r1 = pref_g + ((size_t)(band + 1) * BATCH + batch) * BPB;
        p0 = r0[t];
        p1 = r1[t];
    }
    for (int x = t; x < BPX; x += RTHREADS) win[x] = 0u;

    unsigned int mycnt = 0u;
    if (t < BPB) {
        segbase[t] = (unsigned int)((batch * BPB + t) * EVPB) + p0;
        mycnt = p1 - p0;
    }
    if (t < 64) {                            // wave-0 inclusive scan of 62 counts
        unsigned int v = mycnt;
        for (int d = 1; d < 64; d <<= 1) {
            unsigned int n = __shfl_up(v, d);
            if (t >= d) v += n;
        }
        if (t == 0) segpref[0] = 0u;
        segpref[t + 1] = v;
    }
    __syncthreads();

    unsigned int total = segpref[BPB];       // ~2083
    for (unsigned int j = t; j < total; j += RTHREADS) {
        int lo = 0, hi = BPB - 1;            // largest s with segpref[s] <= j
        while (lo < hi) {
            int mid = (lo + hi + 1) >> 1;
            if (segpref[mid] <= j) lo = mid; else hi = mid - 1;
        }
        unsigned int pk = bins[segbase[lo] + (j - segpref[lo])];
        atomicMax(&win[pk >> 20], pk & 0xFFFFFu);   // LDS atomic
    }
    __syncthreads();

    // write three image rows: 3840 px * 3 ch = 2880 float4; one float4 per
    // thread per iteration -> lane-contiguous 1024B per store instruction
    f4* orow = (f4*)out + (size_t)bandid * (BPX * 3 / 4);
    for (int j = t; j < BPX * 3 / 4; j += RTHREADS) {
        float vals[4];
#pragma unroll
        for (int c = 0; c < 4; ++c) {
            int fi = j * 4 + c;
            int px = fi / 3;
            int ch = fi - px * 3;
            unsigned int k = win[px];
            float val;
            if (k == 0u) val = (ch == 2) ? 510.0f : 255.0f;
            else if (ch == 2) val = 255.0f;
            else if (ch == 0) val = (k & 1u) ? 0.0f : 255.0f;
            else              val = (k & 1u) ? 255.0f : 0.0f;
            vals[c] = val;
        }
        f4 o = { vals[0], vals[1], vals[2], vals[3] };
        __builtin_nontemporal_store(o, orow + j);
    }
}

extern "C" void kernel_launch(void* const* d_in, const int* in_sizes, int n_in,
                              void* d_out, int out_size, void* d_ws, size_t ws_size,
                              hipStream_t stream) {
    const float4* ev = (const float4*)d_in[0];
    unsigned int* pref_g = (unsigned int*)d_ws;
    unsigned int* bins   = (unsigned int*)((char*)d_ws + 0x400000);
    float4* out = (float4*)d_out;

    scatter_k<<<NBLK, THREADS, 0, stream>>>(ev, pref_g, bins);
    render_k<<<BATCH * NBANDS, RTHREADS, 0, stream>>>(pref_g, bins, out);
}